// Round 3
// baseline (189.575 us; speedup 1.0000x reference)
//
#include <hip/hip_runtime.h>

// Fused grouped-QKV GEMM: out[t,kv,g,d] = sum_e in[t,e]*W[e,kv,g,d] + bias
// M=64, K=4096, N=6144. fp32 in/out. Weight read (100.7MB) dominates ->
// memory-bound floor ~16.5us @6.3TB/s.
//
// R2 lesson: 17% BW, VGPR=32 -> compiler kept ~1 wave-load in flight/lane;
// latency-bound (in-flight/latency model matches 1.4TB/s exactly).
// R3: (a) explicit register double-buffer so iter i+1's 12 loads are in
// flight while iter i computes (pure-SSA bf16 pack, no union);
// (b) split-K x4 -> 1536 blocks = 6 blocks/CU for TLP.

#define N_COLS 6144
#define K_DIM  4096
#define Q_SZ   (64 * 4096)
#define K_OFF  Q_SZ
#define V_OFF  (Q_SZ + 64 * 1024)
#define OUT_ELEMS 393216   // 64*6144
#define IN_ELEMS  262144   // 64*4096
#define KSPLIT 4           // k-quarter blocks per n-tile
#define KW     256         // k per wave: 4096/KSPLIT/4 waves
#define NIT    (KW / 32)   // 8 MFMA iterations per wave

typedef __bf16 bf16x8 __attribute__((ext_vector_type(8)));
typedef float  f32x4  __attribute__((ext_vector_type(4)));
typedef unsigned short us8 __attribute__((ext_vector_type(8)));
typedef unsigned int   u32x4 __attribute__((ext_vector_type(4)));

// bf16 copy of the input, rewritten by init_kernel on every call
__device__ unsigned short g_abuf[IN_ELEMS];

__device__ __forceinline__ unsigned short f2bf_rne(float f) {
    unsigned int u = __float_as_uint(f);
    u += 0x7FFFu + ((u >> 16) & 1u);
    return (unsigned short)(u >> 16);
}

__device__ __forceinline__ int out_index(int t, int n) {
    const int kv = n / 768;
    const int g  = (n >> 7) % 6;
    const int d  = n & 127;
    if (g < 4)  return t * 4096 + kv * 512 + g * 128 + d;   // q
    if (g == 4) return K_OFF + t * 1024 + kv * 128 + d;     // k
    return V_OFF + t * 1024 + kv * 128 + d;                 // v
}

// out <- bias broadcast (so gemm can atomicAdd); g_abuf <- bf16(in)
__global__ __launch_bounds__(256)
void init_kernel(const float* __restrict__ in, const float* __restrict__ bias,
                 float* __restrict__ out) {
    const int i = blockIdx.x * 256 + threadIdx.x;
    if (i < IN_ELEMS) g_abuf[i] = f2bf_rne(in[i]);
    if (i < OUT_ELEMS) {
        const int d   = i & 127;
        const int g   = (i >> 7) % 6;
        const int kvt = i / 768;
        const int kv  = kvt & 7;
        const int t   = kvt >> 3;
        out[out_index(t, kv * 768 + g * 128 + d)] = bias[(kv * 6 + g) * 128 + d];
    }
}

__device__ __forceinline__ bf16x8 pack_bf16(const float* b) {
    u32x4 pk;
    #pragma unroll
    for (int j = 0; j < 4; ++j) {
        const unsigned int lo = __float_as_uint(b[2 * j])     + 0x8000u;
        const unsigned int hi = __float_as_uint(b[2 * j + 1]) + 0x8000u;
        pk[j] = (hi & 0xFFFF0000u) | (lo >> 16);
    }
    return __builtin_bit_cast(bf16x8, pk);
}

__global__ __launch_bounds__(256, 5)
void qkv_gemm(const float* __restrict__ w, float* __restrict__ out) {
    __shared__ float red[4][64][17];  // +1 pad: conflict-free reduce

    const int tid  = threadIdx.x;
    const int nt   = blockIdx.x >> 2;   // n-tile 0..383
    const int kq   = blockIdx.x & 3;    // k quarter
    const int n0   = nt * 16;
    const int wid  = tid >> 6;
    const int lane = tid & 63;
    const int l15  = lane & 15;
    const int kblk = lane >> 4;
    const int ks   = kq * 1024 + wid * KW;  // this wave's k-split

    f32x4 acc[4] = {{0.f,0.f,0.f,0.f},{0.f,0.f,0.f,0.f},
                    {0.f,0.f,0.f,0.f},{0.f,0.f,0.f,0.f}};

    const float* bbase = w + (size_t)(ks + kblk * 8) * N_COLS + n0 + l15;
    const unsigned short* abase = g_abuf + l15 * K_DIM + ks + kblk * 8;

    // prologue: iteration 0's loads
    float bc[8];
    us8   ac[4];
    #pragma unroll
    for (int j = 0; j < 8; ++j) bc[j] = bbase[(size_t)j * N_COLS];
    #pragma unroll
    for (int t = 0; t < 4; ++t) ac[t] = *(const us8*)(abase + t * 16 * K_DIM);

    #pragma unroll
    for (int it = 0; it < NIT; ++it) {
        // issue iteration it+1's loads BEFORE consuming iteration it
        float bn[8];
        us8   an[4];
        if (it + 1 < NIT) {
            const float* bp = bbase + (size_t)(32 * (it + 1)) * N_COLS;
            #pragma unroll
            for (int j = 0; j < 8; ++j) bn[j] = bp[(size_t)j * N_COLS];
            const unsigned short* ap = abase + 32 * (it + 1);
            #pragma unroll
            for (int t = 0; t < 4; ++t) an[t] = *(const us8*)(ap + t * 16 * K_DIM);
        }

        // consume current: B[k=kblk*8+j][n=l15], A[m=l15][k=kblk*8+j]
        const bf16x8 bf = pack_bf16(bc);
        acc[0] = __builtin_amdgcn_mfma_f32_16x16x32_bf16(
                     __builtin_bit_cast(bf16x8, ac[0]), bf, acc[0], 0, 0, 0);
        acc[1] = __builtin_amdgcn_mfma_f32_16x16x32_bf16(
                     __builtin_bit_cast(bf16x8, ac[1]), bf, acc[1], 0, 0, 0);
        acc[2] = __builtin_amdgcn_mfma_f32_16x16x32_bf16(
                     __builtin_bit_cast(bf16x8, ac[2]), bf, acc[2], 0, 0, 0);
        acc[3] = __builtin_amdgcn_mfma_f32_16x16x32_bf16(
                     __builtin_bit_cast(bf16x8, ac[3]), bf, acc[3], 0, 0, 0);

        if (it + 1 < NIT) {
            #pragma unroll
            for (int j = 0; j < 8; ++j) bc[j] = bn[j];
            #pragma unroll
            for (int t = 0; t < 4; ++t) ac[t] = an[t];
        }
    }

    // reduce the 4 waves' partials (4 k-sub-splits of this block) in LDS
    #pragma unroll
    for (int tc = 0; tc < 4; ++tc)
        #pragma unroll
        for (int r = 0; r < 4; ++r)
            red[wid][lane][tc * 4 + r] = acc[tc][r];
    __syncthreads();

    const int l  = tid & 63;
    const int i0 = (tid >> 6) * 4;
    const int rl15  = l & 15;
    const int rkblk = l >> 4;
    #pragma unroll
    for (int r2 = 0; r2 < 4; ++r2) {
        const int i = i0 + r2;
        const float s = red[0][l][i] + red[1][l][i] + red[2][l][i] + red[3][l][i];
        const int tc = i >> 2, r = i & 3;
        const int t = tc * 16 + rkblk * 4 + r;          // C/D: row = quad*4+reg
        atomicAdd(&out[out_index(t, n0 + rl15)], s);    // KSPLIT contributions/elem
    }
}

extern "C" void kernel_launch(void* const* d_in, const int* in_sizes, int n_in,
                              void* d_out, int out_size, void* d_ws, size_t ws_size,
                              hipStream_t stream) {
    const float* in   = (const float*)d_in[0];  // [64, 4096]
    const float* w    = (const float*)d_in[1];  // [4096, 8, 6, 128]
    const float* bias = (const float*)d_in[2];  // [8, 6, 128]
    float* out = (float*)d_out;

    init_kernel<<<(OUT_ELEMS + 255) / 256, 256, 0, stream>>>(in, bias, out);
    qkv_gemm<<<384 * KSPLIT, 256, 0, stream>>>(w, out);
}

// Round 4
// 186.509 us; speedup vs baseline: 1.0164x; 1.0164x over previous
//
#include <hip/hip_runtime.h>

// Fused grouped-QKV GEMM: out[t,kv,g,d] = sum_e in[t,e]*W[e,kv,g,d] + bias
// M=64, K=4096, N=6144. fp32 in/out. Weight read (100.7MB) dominates ->
// memory-bound floor ~16.5us @6.3TB/s.
//
// R2/R3 lesson: compiler caps per-wave MLP at ~1 (VGPR=32/40, BW pinned at
// 1.38 TB/s = in-flight/latency with ~1 req/wave). Source-level double
// buffering cannot force batching. R4: inline-asm global loads (invisible
// to the waitcnt pass) + hand-placed s_waitcnt vmcnt(12)/vmcnt(0), tied to
// the loaded regs via "+v" so ordering is enforced by data deps. X/Y batch
// double-buffer -> 12-24 loads in flight per lane.

#define N_COLS 6144
#define K_DIM  4096
#define Q_SZ   (64 * 4096)
#define K_OFF  Q_SZ
#define V_OFF  (Q_SZ + 64 * 1024)
#define OUT_ELEMS 393216   // 64*6144
#define IN_ELEMS  262144   // 64*4096
#define KSPLIT 2           // k-half blocks per n-tile -> 768 blocks
#define KW     512         // k per wave: 4096/KSPLIT/4 waves
#define NIT    (KW / 32)   // 16 MFMA iterations per wave

typedef __bf16 bf16x8 __attribute__((ext_vector_type(8)));
typedef float  f32x4  __attribute__((ext_vector_type(4)));
typedef unsigned int u32x4 __attribute__((ext_vector_type(4)));

__device__ unsigned short g_abuf[IN_ELEMS];  // bf16 input, rewritten each call

__device__ __forceinline__ unsigned short f2bf_rne(float f) {
    unsigned int u = __float_as_uint(f);
    u += 0x7FFFu + ((u >> 16) & 1u);
    return (unsigned short)(u >> 16);
}

__device__ __forceinline__ int out_index(int t, int n) {
    const int kv = n / 768;
    const int g  = (n >> 7) % 6;
    const int d  = n & 127;
    if (g < 4)  return t * 4096 + kv * 512 + g * 128 + d;   // q
    if (g == 4) return K_OFF + t * 1024 + kv * 128 + d;     // k
    return V_OFF + t * 1024 + kv * 128 + d;                 // v
}

__global__ __launch_bounds__(256)
void init_kernel(const float* __restrict__ in, const float* __restrict__ bias,
                 float* __restrict__ out) {
    const int i = blockIdx.x * 256 + threadIdx.x;
    if (i < IN_ELEMS) g_abuf[i] = f2bf_rne(in[i]);
    if (i < OUT_ELEMS) {
        const int d   = i & 127;
        const int g   = (i >> 7) % 6;
        const int kvt = i / 768;
        const int kv  = kvt & 7;
        const int t   = kvt >> 3;
        out[out_index(t, kv * 768 + g * 128 + d)] = bias[(kv * 6 + g) * 128 + d];
    }
}

__device__ __forceinline__ bf16x8 pack8(float f0, float f1, float f2, float f3,
                                        float f4, float f5, float f6, float f7) {
    u32x4 pk;
    const float fs[8] = {f0, f1, f2, f3, f4, f5, f6, f7};
    #pragma unroll
    for (int j = 0; j < 4; ++j) {
        const unsigned int lo = __float_as_uint(fs[2 * j])     + 0x8000u;
        const unsigned int hi = __float_as_uint(fs[2 * j + 1]) + 0x8000u;
        pk[j] = (hi & 0xFFFF0000u) | (lo >> 16);
    }
    return __builtin_bit_cast(bf16x8, pk);
}

// ---- inline-asm load batch: 8 B dwords (k-strided cols) + 4 A dwordx4 ----
#define ISSUE(P, kk) do {                                                     \
    const float* _bp = bbase + (size_t)(kk) * N_COLS;                         \
    asm volatile("global_load_dword %0, %1, off" : "=v"(P##_b0) : "v"(_bp + 0 * (size_t)N_COLS)); \
    asm volatile("global_load_dword %0, %1, off" : "=v"(P##_b1) : "v"(_bp + 1 * (size_t)N_COLS)); \
    asm volatile("global_load_dword %0, %1, off" : "=v"(P##_b2) : "v"(_bp + 2 * (size_t)N_COLS)); \
    asm volatile("global_load_dword %0, %1, off" : "=v"(P##_b3) : "v"(_bp + 3 * (size_t)N_COLS)); \
    asm volatile("global_load_dword %0, %1, off" : "=v"(P##_b4) : "v"(_bp + 4 * (size_t)N_COLS)); \
    asm volatile("global_load_dword %0, %1, off" : "=v"(P##_b5) : "v"(_bp + 5 * (size_t)N_COLS)); \
    asm volatile("global_load_dword %0, %1, off" : "=v"(P##_b6) : "v"(_bp + 6 * (size_t)N_COLS)); \
    asm volatile("global_load_dword %0, %1, off" : "=v"(P##_b7) : "v"(_bp + 7 * (size_t)N_COLS)); \
    const unsigned short* _ap = abase + (kk);                                 \
    asm volatile("global_load_dwordx4 %0, %1, off" : "=v"(P##_a0) : "v"(_ap + 0 * 16 * K_DIM));   \
    asm volatile("global_load_dwordx4 %0, %1, off" : "=v"(P##_a1) : "v"(_ap + 1 * 16 * K_DIM));   \
    asm volatile("global_load_dwordx4 %0, %1, off" : "=v"(P##_a2) : "v"(_ap + 2 * 16 * K_DIM));   \
    asm volatile("global_load_dwordx4 %0, %1, off" : "=v"(P##_a3) : "v"(_ap + 3 * 16 * K_DIM));   \
} while (0)

#define WAITB(P, cnt) \
    asm volatile("s_waitcnt vmcnt(" #cnt ")"                                  \
                 : "+v"(P##_b0), "+v"(P##_b1), "+v"(P##_b2), "+v"(P##_b3),    \
                   "+v"(P##_b4), "+v"(P##_b5), "+v"(P##_b6), "+v"(P##_b7),    \
                   "+v"(P##_a0), "+v"(P##_a1), "+v"(P##_a2), "+v"(P##_a3))

#define CONSUME(P) do {                                                       \
    const bf16x8 _bf = pack8(P##_b0, P##_b1, P##_b2, P##_b3,                  \
                             P##_b4, P##_b5, P##_b6, P##_b7);                 \
    acc[0] = __builtin_amdgcn_mfma_f32_16x16x32_bf16(                         \
                 __builtin_bit_cast(bf16x8, P##_a0), _bf, acc[0], 0, 0, 0);   \
    acc[1] = __builtin_amdgcn_mfma_f32_16x16x32_bf16(                         \
                 __builtin_bit_cast(bf16x8, P##_a1), _bf, acc[1], 0, 0, 0);   \
    acc[2] = __builtin_amdgcn_mfma_f32_16x16x32_bf16(                         \
                 __builtin_bit_cast(bf16x8, P##_a2), _bf, acc[2], 0, 0, 0);   \
    acc[3] = __builtin_amdgcn_mfma_f32_16x16x32_bf16(                         \
                 __builtin_bit_cast(bf16x8, P##_a3), _bf, acc[3], 0, 0, 0);   \
} while (0)

__global__ __launch_bounds__(256, 4)
void qkv_gemm(const float* __restrict__ w, float* __restrict__ out) {
    __shared__ float red[4][64][17];  // +1 pad: conflict-free reduce

    const int tid  = threadIdx.x;
    const int nt   = blockIdx.x >> 1;   // n-tile 0..383
    const int kh   = blockIdx.x & 1;    // k half
    const int n0   = nt * 16;
    const int wid  = tid >> 6;
    const int lane = tid & 63;
    const int l15  = lane & 15;
    const int kblk = lane >> 4;
    const int ks   = kh * 2048 + wid * KW;  // this wave's 512-wide k split

    f32x4 acc[4] = {{0.f,0.f,0.f,0.f},{0.f,0.f,0.f,0.f},
                    {0.f,0.f,0.f,0.f},{0.f,0.f,0.f,0.f}};

    const float* bbase = w + (size_t)(ks + kblk * 8) * N_COLS + n0 + l15;
    const unsigned short* abase = g_abuf + l15 * K_DIM + ks + kblk * 8;

    float X_b0 = 0, X_b1 = 0, X_b2 = 0, X_b3 = 0, X_b4 = 0, X_b5 = 0, X_b6 = 0, X_b7 = 0;
    float Y_b0 = 0, Y_b1 = 0, Y_b2 = 0, Y_b3 = 0, Y_b4 = 0, Y_b5 = 0, Y_b6 = 0, Y_b7 = 0;
    u32x4 X_a0 = {}, X_a1 = {}, X_a2 = {}, X_a3 = {};
    u32x4 Y_a0 = {}, Y_a1 = {}, Y_a2 = {}, Y_a3 = {};

    // software pipeline: X/Y batch double-buffer, 12-24 loads in flight/lane
    ISSUE(X, 0);
    int kk = 0;
    #pragma unroll 1
    for (int j = 0; j < NIT / 2 - 1; ++j) {   // 7 pairs
        ISSUE(Y, kk + 32); WAITB(X, 12); CONSUME(X);
        ISSUE(X, kk + 64); WAITB(Y, 12); CONSUME(Y);
        kk += 64;
    }
    // kk == 448: tail
    ISSUE(Y, kk + 32); WAITB(X, 12); CONSUME(X);
    WAITB(Y, 0);       CONSUME(Y);

    // reduce the 4 waves' partials (k-sub-splits) in LDS
    #pragma unroll
    for (int tc = 0; tc < 4; ++tc)
        #pragma unroll
        for (int r = 0; r < 4; ++r)
            red[wid][lane][tc * 4 + r] = acc[tc][r];
    __syncthreads();

    const int l  = tid & 63;
    const int i0 = (tid >> 6) * 4;
    const int rl15  = l & 15;
    const int rkblk = l >> 4;
    #pragma unroll
    for (int r2 = 0; r2 < 4; ++r2) {
        const int i = i0 + r2;
        const float s = red[0][l][i] + red[1][l][i] + red[2][l][i] + red[3][l][i];
        const int tc = i >> 2, r = i & 3;
        const int t = tc * 16 + rkblk * 4 + r;          // C/D: row = quad*4+reg
        atomicAdd(&out[out_index(t, n0 + rl15)], s);    // KSPLIT contributions/elem
    }
}

extern "C" void kernel_launch(void* const* d_in, const int* in_sizes, int n_in,
                              void* d_out, int out_size, void* d_ws, size_t ws_size,
                              hipStream_t stream) {
    const float* in   = (const float*)d_in[0];  // [64, 4096]
    const float* w    = (const float*)d_in[1];  // [4096, 8, 6, 128]
    const float* bias = (const float*)d_in[2];  // [8, 6, 128]
    float* out = (float*)d_out;

    init_kernel<<<(OUT_ELEMS + 255) / 256, 256, 0, stream>>>(in, bias, out);
    qkv_gemm<<<384 * KSPLIT, 256, 0, stream>>>(w, out);
}

// Round 5
// 182.736 us; speedup vs baseline: 1.0374x; 1.0206x over previous
//
#include <hip/hip_runtime.h>

// Fused grouped-QKV GEMM: out[t,kv,g,d] = sum_e in[t,e]*W[e,kv,g,d] + bias
// M=64, K=4096, N=6144. fp32 in/out. Weight read (100.7MB) dominates ->
// memory-bound floor ~16.5us @6.3TB/s.
//
// R1-R4 lesson: BW pinned at 1.0-1.4 TB/s regardless of scheduling because
// every W load was a 64B segment strided 24KB -> one DRAM row-activate per
// 64B (random-64B ceiling ~1.5 TB/s). R5: n-contiguous staging -- each wave
// load instruction covers a full 1KB run of a k-row (16 sequential 64B txns
// per page) -- with an LDS transpose into MFMA fragment order.
// LDS layout Bs[nb][ktp] (16B cells): dword i of cell nb -> n=4nb+i,
// cell ktp -> k pair (2ktp,2ktp+1). Writes: one conflict-free b128/thread/
// round. Reads: 4x b32/frag, bank-verified 2-way (free).

#define N_COLS 6144
#define K_DIM  4096
#define Q_SZ   (64 * 4096)
#define K_OFF  Q_SZ
#define V_OFF  (Q_SZ + 64 * 1024)
#define OUT_ELEMS 393216   // 64*6144
#define IN_ELEMS  262144   // 64*4096
#define NTILES 24          // n-tiles of 256
#define KSPLIT 32          // -> 768 blocks = 3/CU
#define KSTEPS 4           // 128 k per block, BK=32

typedef __bf16 bf16x8 __attribute__((ext_vector_type(8)));
typedef float  f32x4  __attribute__((ext_vector_type(4)));
typedef unsigned int u32x4 __attribute__((ext_vector_type(4)));

__device__ unsigned short g_abuf[IN_ELEMS];  // bf16 input, rewritten each call

__device__ __forceinline__ unsigned short f2bf_rne(float f) {
    unsigned int u = __float_as_uint(f);
    u += 0x7FFFu + ((u >> 16) & 1u);
    return (unsigned short)(u >> 16);
}

__device__ __forceinline__ int out_index(int t, int n) {
    const int kv = n / 768;
    const int g  = (n >> 7) % 6;
    const int d  = n & 127;
    if (g < 4)  return t * 4096 + kv * 512 + g * 128 + d;   // q
    if (g == 4) return K_OFF + t * 1024 + kv * 128 + d;     // k
    return V_OFF + t * 1024 + kv * 128 + d;                 // v
}

__global__ __launch_bounds__(256)
void init_kernel(const float* __restrict__ in, const float* __restrict__ bias,
                 float* __restrict__ out) {
    const int i = blockIdx.x * 256 + threadIdx.x;
    if (i < IN_ELEMS) g_abuf[i] = f2bf_rne(in[i]);
    if (i < OUT_ELEMS) {
        const int d   = i & 127;
        const int g   = (i >> 7) % 6;
        const int kvt = i / 768;
        const int kv  = kvt & 7;
        const int t   = kvt >> 3;
        out[out_index(t, kv * 768 + g * 128 + d)] = bias[(kv * 6 + g) * 128 + d];
    }
}

__device__ __forceinline__ unsigned int pack_pair(float lo, float hi) {
    // dword = bf16(lo) | bf16(hi)<<16   (k, k+1 pair)
    return ((unsigned int)f2bf_rne(hi) << 16) | f2bf_rne(lo);
}

__global__ __launch_bounds__(256, 3)
void qkv_gemm(const float* __restrict__ w, float* __restrict__ out) {
    // [nb 0..63][ktp 0..15 + 1 pad] cells of 16B -> 17408 B
    __shared__ u32x4 Bs[64][17];

    const int tid  = threadIdx.x;
    const int nt   = blockIdx.x % NTILES;   // adjacent blocks: adjacent n, same k
    const int kq   = blockIdx.x / NTILES;
    const int n0   = nt * 256;
    const int k0   = kq * (KSTEPS * 32);

    const int wid  = tid >> 6;
    const int lane = tid & 63;
    const int l15  = lane & 15;
    const int kblk = lane >> 4;

    f32x4 acc[16];
    #pragma unroll
    for (int i = 0; i < 16; ++i) acc[i] = (f32x4){0.f, 0.f, 0.f, 0.f};

    // staging: round r covers tile rows {r*8+2*wid, +1}, cols 4*lane..+3.
    // each wave-instr = 1KB contiguous of one k-row (the DRAM fix).
    const float* wbase = w + (size_t)(k0 + 2 * wid) * N_COLS + n0 + 4 * lane;
    const unsigned short* abase = g_abuf + (wid * 16 + l15) * K_DIM + k0 + kblk * 8;

    float4 Lc[8], Ln[8];
    u32x4  Ac, An;

    #pragma unroll
    for (int r = 0; r < 4; ++r) {
        Lc[2 * r]     = *(const float4*)(wbase + (size_t)(r * 8) * N_COLS);
        Lc[2 * r + 1] = *(const float4*)(wbase + (size_t)(r * 8 + 1) * N_COLS);
    }
    Ac = *(const u32x4*)abase;

    const unsigned int* bsr = (const unsigned int*)&Bs[0][0];
    const int q = l15 >> 2, ii = l15 & 3;

    #pragma unroll
    for (int s = 0; s < KSTEPS; ++s) {
        // pack current tile -> LDS (one b128 per round, conflict-free)
        #pragma unroll
        for (int r = 0; r < 4; ++r) {
            const float4 ra = Lc[2 * r], rb = Lc[2 * r + 1];
            u32x4 cell;
            cell[0] = pack_pair(ra.x, rb.x);
            cell[1] = pack_pair(ra.y, rb.y);
            cell[2] = pack_pair(ra.z, rb.z);
            cell[3] = pack_pair(ra.w, rb.w);
            Bs[lane][r * 4 + wid] = cell;   // ktp = (r*8+2*wid)/2
        }
        // issue next K-step's loads (cover = compute below + barriers)
        if (s + 1 < KSTEPS) {
            const float* wn = wbase + (size_t)((s + 1) * 32) * N_COLS;
            #pragma unroll
            for (int r = 0; r < 4; ++r) {
                Ln[2 * r]     = *(const float4*)(wn + (size_t)(r * 8) * N_COLS);
                Ln[2 * r + 1] = *(const float4*)(wn + (size_t)(r * 8 + 1) * N_COLS);
            }
            An = *(const u32x4*)(abase + (s + 1) * 32);
        }
        __syncthreads();  // tile staged

        const bf16x8 af = __builtin_bit_cast(bf16x8, Ac);
        #pragma unroll
        for (int nf = 0; nf < 16; ++nf) {
            // lane needs n = nf*16 + l15 = 4*(4nf+q) + ii, k = kblk*8..+7
            const unsigned int base = (unsigned)(((nf * 4 + q) * 17 + kblk * 4) * 4 + ii);
            u32x4 bu;
            bu[0] = bsr[base];
            bu[1] = bsr[base + 4];
            bu[2] = bsr[base + 8];
            bu[3] = bsr[base + 12];
            acc[nf] = __builtin_amdgcn_mfma_f32_16x16x32_bf16(
                          af, __builtin_bit_cast(bf16x8, bu), acc[nf], 0, 0, 0);
        }
        __syncthreads();  // reads done; buffer reusable

        if (s + 1 < KSTEPS) {
            #pragma unroll
            for (int r = 0; r < 8; ++r) Lc[r] = Ln[r];
            Ac = An;
        }
    }

    // epilogue: C/D col = n-offset l15, row = kblk*4 + reg -> token
    #pragma unroll
    for (int nf = 0; nf < 16; ++nf) {
        const int nb = n0 + nf * 16;
        const int kv = nb / 768;
        const int g  = (nb >> 7) % 6;
        const int d  = (nb & 127) + l15;
        int base, tstride;
        if (g < 4)       { base = kv * 512 + g * 128 + d;  tstride = 4096; }
        else if (g == 4) { base = K_OFF + kv * 128 + d;    tstride = 1024; }
        else             { base = V_OFF + kv * 128 + d;    tstride = 1024; }
        const int t0 = wid * 16 + kblk * 4;
        #pragma unroll
        for (int r = 0; r < 4; ++r)
            atomicAdd(&out[base + (t0 + r) * tstride], acc[nf][r]);
    }
}

extern "C" void kernel_launch(void* const* d_in, const int* in_sizes, int n_in,
                              void* d_out, int out_size, void* d_ws, size_t ws_size,
                              hipStream_t stream) {
    const float* in   = (const float*)d_in[0];  // [64, 4096]
    const float* w    = (const float*)d_in[1];  // [4096, 8, 6, 128]
    const float* bias = (const float*)d_in[2];  // [8, 6, 128]
    float* out = (float*)d_out;

    init_kernel<<<(OUT_ELEMS + 255) / 256, 256, 0, stream>>>(in, bias, out);
    qkv_gemm<<<NTILES * KSPLIT, 256, 0, stream>>>(w, out);
}